// Round 9
// baseline (504.572 us; speedup 1.0000x reference)
//
#include <hip/hip_runtime.h>

#define N_NODES 50000
#define N_EDGES 800000
#define D_IN 256
#define D_OUT 64
#define NEG_SLOPE 0.2f

#define GRID 896          // <= 3.5 blocks/CU; capacity at (256,4)+32KB LDS is 4/CU
                          // = 1024 blocks -> co-residency guaranteed w/ margin
#define GEMM_BLOCKS 782   // ceil(50000/64), one 64-row tile per block
#define N_GROUPS 12500    // ceil(50000/4), 4 nodes (waves) per block in agg

typedef __attribute__((ext_vector_type(8))) short bf16x8;   // 8 bf16 = 4 VGPR
typedef __attribute__((ext_vector_type(4))) float f32x4;    // MFMA C/D + NT I/O
typedef __attribute__((ext_vector_type(4))) ushort u16x4;   // 8B gather chunk

__device__ inline ushort f2bf(float f) {  // f32 -> bf16, round-nearest-even
  union { float f; unsigned u; } v; v.f = f;
  unsigned r = v.u + 0x7FFFu + ((v.u >> 16) & 1u);
  return (ushort)(r >> 16);
}
__device__ inline float bf2f(ushort h) {
  union { unsigned u; float f; } v; v.u = ((unsigned)h) << 16;
  return v.f;
}

// ---------------------------------------------------------------------------
// ONE kernel, two phases, one manual device barrier.
//  Phase A: blocks <782: W f32->bf16 into XOR-swizzled LDS, then MFMA tile.
//           blocks >=782: build CSR row_ptr (runs in gemm's shadow).
//  Barrier: release fence -> device-scope atomic arrive -> acquire spin.
//           Counter zeroed by in-graph hipMemsetAsync (replay-safe).
//  Phase B: all blocks grid-stride the gather-aggregate + LeakyReLU.
// Removes 2 of 3 kernel-boundary drains; overlaps prep with gemm; LDS B-reads
// replace global Wb reads (swizzle: byte ^= (row&7)<<4 -> 2-way max = free).
// ---------------------------------------------------------------------------
__global__ __launch_bounds__(256, 4) void fused_gcn(
    const float* __restrict__ x, const float* __restrict__ W,
    const float* __restrict__ bias,
    const int* __restrict__ edge_src, const int* __restrict__ edge_dst,
    const float* __restrict__ edge_val,
    float* __restrict__ out, ushort* __restrict__ support,
    int* __restrict__ row_ptr, unsigned* __restrict__ bar) {
  __shared__ ushort Wl[D_OUT * D_IN];  // 32 KB, swizzled
  const int tid  = threadIdx.x;
  const int wave = tid >> 6;
  const int lane = tid & 63;
  const int bid  = blockIdx.x;

  // ---------------- Phase A ----------------
  if (bid < GEMM_BLOCKS) {
    // W -> LDS (bf16, swizzled). 2048 chunks of 8 elems; 8 iters/thread.
    for (int c = tid; c < (D_OUT * D_IN) / 8; c += 256) {
      const int row = c >> 5;           // 32 eight-elem chunks per 256-col row
      const int cc  = c & 31;
      const f32x4 w0 = *reinterpret_cast<const f32x4*>(W + c * 8);
      const f32x4 w1 = *reinterpret_cast<const f32x4*>(W + c * 8 + 4);
      bf16x8 v;
      v[0] = (short)f2bf(w0[0]); v[1] = (short)f2bf(w0[1]);
      v[2] = (short)f2bf(w0[2]); v[3] = (short)f2bf(w0[3]);
      v[4] = (short)f2bf(w1[0]); v[5] = (short)f2bf(w1[1]);
      v[6] = (short)f2bf(w1[2]); v[7] = (short)f2bf(w1[3]);
      unsigned byte = row * 512 + cc * 16;
      byte ^= (row & 7) << 4;           // st-swizzle
      *reinterpret_cast<bf16x8*>(reinterpret_cast<char*>(Wl) + byte) = v;
    }
    __syncthreads();

    // MFMA tile: 16x64 per wave, deep-preloaded A from global x.
    const int m0  = bid * 64 + wave * 16;
    const int r16 = lane & 15;
    const int kg  = lane >> 4;
    int arow = m0 + r16;
    if (arow >= N_NODES) arow = N_NODES - 1;  // clamp; stores guarded
    const float* xp = x + (size_t)arow * D_IN + kg * 8;

    f32x4 xd[16];
#pragma unroll
    for (int ks = 0; ks < 8; ++ks) {
      xd[2 * ks]     = __builtin_nontemporal_load(
          reinterpret_cast<const f32x4*>(xp + ks * 32));
      xd[2 * ks + 1] = __builtin_nontemporal_load(
          reinterpret_cast<const f32x4*>(xp + ks * 32 + 4));
    }

    f32x4 acc[4] = {f32x4{0.f,0.f,0.f,0.f}, f32x4{0.f,0.f,0.f,0.f},
                    f32x4{0.f,0.f,0.f,0.f}, f32x4{0.f,0.f,0.f,0.f}};
#pragma unroll
    for (int ks = 0; ks < 8; ++ks) {
      const f32x4 xa = xd[2 * ks];
      const f32x4 xb = xd[2 * ks + 1];
      bf16x8 a;
      a[0] = (short)f2bf(xa[0]); a[1] = (short)f2bf(xa[1]);
      a[2] = (short)f2bf(xa[2]); a[3] = (short)f2bf(xa[3]);
      a[4] = (short)f2bf(xb[0]); a[5] = (short)f2bf(xb[1]);
      a[6] = (short)f2bf(xb[2]); a[7] = (short)f2bf(xb[3]);
#pragma unroll
      for (int nb = 0; nb < 4; ++nb) {
        const int row = nb * 16 + r16;
        unsigned byte = row * 512 + kg * 16 + ks * 64;  // same lane->k map as A
        byte ^= (row & 7) << 4;                          // ld-swizzle
        const bf16x8 bfrag = *reinterpret_cast<const bf16x8*>(
            reinterpret_cast<const char*>(Wl) + byte);
        acc[nb] =
            __builtin_amdgcn_mfma_f32_16x16x32_bf16(a, bfrag, acc[nb], 0, 0, 0);
      }
    }
#pragma unroll
    for (int nb = 0; nb < 4; ++nb) {
      const int col = nb * 16 + r16;
      const float bv = bias[col];
#pragma unroll
      for (int i = 0; i < 4; ++i) {
        const int row = m0 + kg * 4 + i;  // C/D: col=lane&15, row=(lane>>4)*4+reg
        if (row < N_NODES)
          support[(size_t)row * D_OUT + col] = f2bf(acc[nb][i] + bv);
      }
    }
  } else {
    // CSR row_ptr from sorted edge_dst (114 blocks, ~28 iters/thread).
    for (int e = (bid - GEMM_BLOCKS) * 256 + tid; e < N_EDGES;
         e += (GRID - GEMM_BLOCKS) * 256) {
      const int d = __builtin_nontemporal_load(edge_dst + e);
      if (e == 0) {
        for (int n = 0; n <= d; ++n) row_ptr[n] = 0;
      } else {
        const int dp = __builtin_nontemporal_load(edge_dst + e - 1);
        if (d != dp)
          for (int n = dp + 1; n <= d; ++n) row_ptr[n] = e;
      }
      if (e == N_EDGES - 1)
        for (int n = d + 1; n <= N_NODES; ++n) row_ptr[n] = N_EDGES;
    }
  }

  // ---------------- device barrier ----------------
  __threadfence();        // release: drain + make this thread's stores visible
  __syncthreads();        // all waves of the block past their fence
  if (tid == 0) {
    __hip_atomic_fetch_add(bar, 1u, __ATOMIC_ACQ_REL, __HIP_MEMORY_SCOPE_AGENT);
    while (__hip_atomic_load(bar, __ATOMIC_ACQUIRE, __HIP_MEMORY_SCOPE_AGENT) <
           (unsigned)GRID)
      __builtin_amdgcn_s_sleep(2);
  }
  __syncthreads();
  __threadfence();        // acquire side for all threads (inv L1/L2)

  // ---------------- Phase B: aggregate + LeakyReLU ----------------
  // One wave per node; lane=(eg=lane>>4, cl=lane&15); one gather inst =
  // 4 edges' full 128B rows. Tail branchless. shfl_xor(16,32) reduce.
  const int eg = lane >> 4;
  const int cl = lane & 15;
  for (int ngrp = bid; ngrp < N_GROUPS; ngrp += GRID) {
    const int wid = ngrp * 4 + wave;
    if (wid >= N_NODES) continue;
    const int lo = row_ptr[wid];
    const int hi = row_ptr[wid + 1];

    f32x4 acc0 = {0.f, 0.f, 0.f, 0.f};
    f32x4 acc1 = {0.f, 0.f, 0.f, 0.f};
    for (int e = lo; e < hi; e += 16) {
      int   s[4];
      float v[4];
#pragma unroll
      for (int q = 0; q < 4; ++q) {
        const int idx = e + q * 4 + eg;
        const int ic = idx < hi ? idx : hi - 1;   // hi>lo inside loop
        s[q] = __builtin_nontemporal_load(edge_src + ic);
        const float vv = __builtin_nontemporal_load(edge_val + ic);
        v[q] = idx < hi ? vv : 0.f;
      }
#pragma unroll
      for (int q = 0; q < 4; ++q) {
        const u16x4 g = *reinterpret_cast<const u16x4*>(
            support + (size_t)s[q] * D_OUT + cl * 4);
        f32x4& acc = (q & 1) ? acc1 : acc0;
        acc[0] = fmaf(v[q], bf2f(g[0]), acc[0]);
        acc[1] = fmaf(v[q], bf2f(g[1]), acc[1]);
        acc[2] = fmaf(v[q], bf2f(g[2]), acc[2]);
        acc[3] = fmaf(v[q], bf2f(g[3]), acc[3]);
      }
    }

    float r[4] = {acc0[0] + acc1[0], acc0[1] + acc1[1],
                  acc0[2] + acc1[2], acc0[3] + acc1[3]};
#pragma unroll
    for (int c = 0; c < 4; ++c) {
      r[c] += __shfl_xor(r[c], 16, 64);
      r[c] += __shfl_xor(r[c], 32, 64);
      r[c] = r[c] >= 0.f ? r[c] : NEG_SLOPE * r[c];
    }
    if (eg == 0) {
      f32x4 o = {r[0], r[1], r[2], r[3]};
      __builtin_nontemporal_store(
          o, reinterpret_cast<f32x4*>(out + (size_t)wid * D_OUT + cl * 4));
    }
  }
}

// ---------------------------------------------------------------------------
extern "C" void kernel_launch(void* const* d_in, const int* in_sizes, int n_in,
                              void* d_out, int out_size, void* d_ws, size_t ws_size,
                              hipStream_t stream) {
  const float* x        = (const float*)d_in[0];
  const float* W        = (const float*)d_in[1];
  const float* b        = (const float*)d_in[2];
  const int*   edge_src = (const int*)d_in[3];
  const int*   edge_dst = (const int*)d_in[4];
  const float* edge_val = (const float*)d_in[5];
  float* out = (float*)d_out;

  // workspace layout
  ushort* support = (ushort*)d_ws;                                  // 6.4 MB
  char* p = (char*)d_ws + (size_t)N_NODES * D_OUT * sizeof(ushort);
  int* row_ptr = (int*)p;                                           // 200 KB
  p += (size_t)(N_NODES + 1) * sizeof(int);
  p = (char*)(((uintptr_t)p + 63) & ~(uintptr_t)63);
  unsigned* bar = (unsigned*)p;                                     // 64 B

  // Zero the barrier counter IN-GRAPH each call (replay-safe, poison-safe).
  hipMemsetAsync(bar, 0, 64, stream);

  hipLaunchKernelGGL(fused_gcn, dim3(GRID), dim3(256), 0, stream,
                     x, W, b, edge_src, edge_dst, edge_val,
                     out, support, row_ptr, bar);
}

// Round 10
// 104.432 us; speedup vs baseline: 4.8316x; 4.8316x over previous
//
#include <hip/hip_runtime.h>

#define N_NODES 50000
#define N_EDGES 800000
#define D_IN 256
#define D_OUT 64
#define NEG_SLOPE 0.2f

#define GEMM_BLOCKS 782   // ceil(50000/64), one 64-row tile per block
#define PREP_BLOCKS 114   // row_ptr builder blocks appended to gemm grid
#define GRID1 (GEMM_BLOCKS + PREP_BLOCKS)

typedef __attribute__((ext_vector_type(8))) short bf16x8;   // 8 bf16 = 4 VGPR
typedef __attribute__((ext_vector_type(4))) float f32x4;    // MFMA C/D

__device__ inline ushort f2bf(float f) {  // f32 -> bf16, round-nearest-even
  union { float f; unsigned u; } v; v.f = f;
  unsigned r = v.u + 0x7FFFu + ((v.u >> 16) & 1u);
  return (ushort)(r >> 16);
}
__device__ inline float bf2f(ushort h) {
  union { unsigned u; float f; } v; v.u = ((unsigned)h) << 16;
  return v.f;
}

// ---------------------------------------------------------------------------
// Kernel 1 (prep fused into gemm grid; NO inter-block dependency):
//  blocks <782 : stage W f32->bf16 into XOR-swizzled LDS (validated in R9),
//                then one 16x64 MFMA tile per wave. Plain (non-NT) x loads so
//                L1 catches the xa/xb shared-64B-line reuse.
//  blocks >=782: build CSR row_ptr from sorted edge_dst (consumed only by the
//                NEXT dispatch -> kernel boundary is the sync).
// Launched 3x this round (idempotent) for timing attribution of the gemm.
// ---------------------------------------------------------------------------
__global__ __launch_bounds__(256, 4) void gemm_prep(
    const float* __restrict__ x, const float* __restrict__ W,
    const float* __restrict__ bias,
    const int* __restrict__ edge_dst, int* __restrict__ row_ptr,
    ushort* __restrict__ support) {
  const int tid  = threadIdx.x;
  const int bid  = blockIdx.x;

  if (bid >= GEMM_BLOCKS) {
    // ---- prep: CSR row_ptr ----
    for (int e = (bid - GEMM_BLOCKS) * 256 + tid; e < N_EDGES;
         e += PREP_BLOCKS * 256) {
      const int d = edge_dst[e];
      if (e == 0) {
        for (int n = 0; n <= d; ++n) row_ptr[n] = 0;
      } else {
        const int dp = edge_dst[e - 1];
        if (d != dp)
          for (int n = dp + 1; n <= d; ++n) row_ptr[n] = e;
      }
      if (e == N_EDGES - 1)
        for (int n = d + 1; n <= N_NODES; ++n) row_ptr[n] = N_EDGES;
    }
    return;
  }

  // ---- gemm ----
  __shared__ ushort Wl[D_OUT * D_IN];  // 32 KB, XOR-swizzled
  const int wave = tid >> 6;
  const int lane = tid & 63;

  // W -> LDS (bf16, swizzle byte ^= (row&7)<<4 -> conflict-free b128 reads)
  for (int c = tid; c < (D_OUT * D_IN) / 8; c += 256) {
    const int row = c >> 5;
    const int cc  = c & 31;
    const f32x4 w0 = *reinterpret_cast<const f32x4*>(W + c * 8);
    const f32x4 w1 = *reinterpret_cast<const f32x4*>(W + c * 8 + 4);
    bf16x8 v;
    v[0] = (short)f2bf(w0[0]); v[1] = (short)f2bf(w0[1]);
    v[2] = (short)f2bf(w0[2]); v[3] = (short)f2bf(w0[3]);
    v[4] = (short)f2bf(w1[0]); v[5] = (short)f2bf(w1[1]);
    v[6] = (short)f2bf(w1[2]); v[7] = (short)f2bf(w1[3]);
    unsigned byte = row * 512 + cc * 16;
    byte ^= (row & 7) << 4;
    *reinterpret_cast<bf16x8*>(reinterpret_cast<char*>(Wl) + byte) = v;
  }
  __syncthreads();

  const int m0  = bid * 64 + wave * 16;
  const int r16 = lane & 15;
  const int kg  = lane >> 4;
  int arow = m0 + r16;
  if (arow >= N_NODES) arow = N_NODES - 1;   // clamp; stores guarded
  const float* xp = x + (size_t)arow * D_IN + kg * 8;

  f32x4 acc[4] = {f32x4{0.f,0.f,0.f,0.f}, f32x4{0.f,0.f,0.f,0.f},
                  f32x4{0.f,0.f,0.f,0.f}, f32x4{0.f,0.f,0.f,0.f}};
#pragma unroll
  for (int ks = 0; ks < 8; ++ks) {
    const f32x4 xa = *reinterpret_cast<const f32x4*>(xp + ks * 32);
    const f32x4 xb = *reinterpret_cast<const f32x4*>(xp + ks * 32 + 4);
    bf16x8 a;
    a[0] = (short)f2bf(xa[0]); a[1] = (short)f2bf(xa[1]);
    a[2] = (short)f2bf(xa[2]); a[3] = (short)f2bf(xa[3]);
    a[4] = (short)f2bf(xb[0]); a[5] = (short)f2bf(xb[1]);
    a[6] = (short)f2bf(xb[2]); a[7] = (short)f2bf(xb[3]);
#pragma unroll
    for (int nb = 0; nb < 4; ++nb) {
      const int row = nb * 16 + r16;
      unsigned byte = row * 512 + kg * 16 + ks * 64;   // same lane->k map as A
      byte ^= (row & 7) << 4;
      const bf16x8 bfrag = *reinterpret_cast<const bf16x8*>(
          reinterpret_cast<const char*>(Wl) + byte);
      acc[nb] =
          __builtin_amdgcn_mfma_f32_16x16x32_bf16(a, bfrag, acc[nb], 0, 0, 0);
    }
  }
#pragma unroll
  for (int nb = 0; nb < 4; ++nb) {
    const int col = nb * 16 + r16;
    const float bv = bias[col];
#pragma unroll
    for (int i = 0; i < 4; ++i) {
      const int row = m0 + kg * 4 + i;  // C/D: col=lane&15, row=(lane>>4)*4+reg
      if (row < N_NODES)
        support[(size_t)row * D_OUT + col] = f2bf(acc[nb][i] + bv);
    }
  }
}

// ---------------------------------------------------------------------------
// Aggregation + LeakyReLU — exact R4 structure (best measured: 62.8 total).
// One wave per node, lane = column. 8 independent accumulators -> 8 gathers
// (one 128B row each) in flight. f32 accumulate, fused LeakyReLU.
// ---------------------------------------------------------------------------
__global__ __launch_bounds__(256, 8) void agg_kernel(
    const ushort* __restrict__ support, const int* __restrict__ edge_src,
    const float* __restrict__ edge_val, const int* __restrict__ row_ptr,
    float* __restrict__ out) {
  const int wid = (blockIdx.x * 256 + threadIdx.x) >> 6;
  const int lane = threadIdx.x & 63;
  if (wid >= N_NODES) return;
  const int lo = row_ptr[wid];
  const int hi = row_ptr[wid + 1];

  float a[8];
#pragma unroll
  for (int q = 0; q < 8; ++q) a[q] = 0.f;

  int e = lo;
  for (; e + 7 < hi; e += 8) {
    int   s[8];
    float v[8];
#pragma unroll
    for (int q = 0; q < 8; ++q) { s[q] = edge_src[e + q]; v[q] = edge_val[e + q]; }
#pragma unroll
    for (int q = 0; q < 8; ++q)
      a[q] = fmaf(v[q], bf2f(support[(size_t)s[q] * D_OUT + lane]), a[q]);
  }
  if (e + 3 < hi) {
    int   s[4];
    float v[4];
#pragma unroll
    for (int q = 0; q < 4; ++q) { s[q] = edge_src[e + q]; v[q] = edge_val[e + q]; }
#pragma unroll
    for (int q = 0; q < 4; ++q)
      a[q] = fmaf(v[q], bf2f(support[(size_t)s[q] * D_OUT + lane]), a[q]);
    e += 4;
  }
  for (; e < hi; ++e)
    a[0] = fmaf(edge_val[e], bf2f(support[(size_t)edge_src[e] * D_OUT + lane]), a[0]);

  const float acc = ((a[0] + a[1]) + (a[2] + a[3])) + ((a[4] + a[5]) + (a[6] + a[7]));
  out[(size_t)wid * D_OUT + lane] = acc >= 0.f ? acc : NEG_SLOPE * acc;
}

// ---------------------------------------------------------------------------
extern "C" void kernel_launch(void* const* d_in, const int* in_sizes, int n_in,
                              void* d_out, int out_size, void* d_ws, size_t ws_size,
                              hipStream_t stream) {
  const float* x        = (const float*)d_in[0];
  const float* W        = (const float*)d_in[1];
  const float* b        = (const float*)d_in[2];
  const int*   edge_src = (const int*)d_in[3];
  const int*   edge_dst = (const int*)d_in[4];
  const float* edge_val = (const float*)d_in[5];
  float* out = (float*)d_out;

  // workspace layout
  ushort* support = (ushort*)d_ws;                                  // 6.4 MB
  char* p = (char*)d_ws + (size_t)N_NODES * D_OUT * sizeof(ushort);
  int* row_ptr = (int*)p;                                           // 200 KB

  // ATTRIBUTION PROBE: gemm_prep launched 3x (idempotent — rewrites the same
  // support/row_ptr). dur_us = T_base + 2*g isolates the gemm dispatch cost.
  for (int rep = 0; rep < 3; ++rep)
    hipLaunchKernelGGL(gemm_prep, dim3(GRID1), dim3(256), 0, stream,
                       x, W, b, edge_dst, row_ptr, support);
  hipLaunchKernelGGL(agg_kernel, dim3((N_NODES * 64 + 255) / 256), dim3(256), 0,
                     stream, support, edge_src, edge_val, row_ptr, out);
}

// Round 11
// 57.981 us; speedup vs baseline: 8.7023x; 1.8011x over previous
//
#include <hip/hip_runtime.h>

#define N_NODES 50000
#define N_EDGES 800000
#define D_IN 256
#define D_OUT 64
#define NEG_SLOPE 0.2f

#define GEMM_BLOCKS 782   // ceil(50000/64), one 64-row tile per block
#define PREP_BLOCKS 114   // row_ptr builder blocks appended to gemm grid
#define GRID1 (GEMM_BLOCKS + PREP_BLOCKS)

typedef __attribute__((ext_vector_type(8))) short bf16x8;   // 8 bf16 = 4 VGPR
typedef __attribute__((ext_vector_type(4))) float f32x4;    // MFMA C/D

__device__ inline ushort f2bf(float f) {  // f32 -> bf16, round-nearest-even
  union { float f; unsigned u; } v; v.f = f;
  unsigned r = v.u + 0x7FFFu + ((v.u >> 16) & 1u);
  return (ushort)(r >> 16);
}
__device__ inline float bf2f(ushort h) {
  union { unsigned u; float f; } v; v.u = ((unsigned)h) << 16;
  return v.f;
}

// ---------------------------------------------------------------------------
// Kernel 1: gemm (blocks <782) + row_ptr prep (blocks >=782, consumed only by
// the NEXT dispatch).
// gemm per wave = one 16x64 tile. ORDER OF OPERATIONS IS THE OPTIMIZATION:
//   1) issue ALL 16 x-loads (256B/lane) back-to-back
//   2) sched_barrier(0)  -- compiler may NOT sink the loads past this point;
//      forces 16 outstanding HBM loads/wave (64 VGPRs live) instead of the
//      2-deep pipeline it chose in R8-R10 (VGPR_Count 44-48 proved the sink)
//   3) W f32->bf16 into XOR-swizzled LDS -- its L2 loads + converts + barrier
//      execute UNDER the x-miss latency
//   4) consume x from registers: convert + 32 MFMA, epilogue.
// ---------------------------------------------------------------------------
__global__ __launch_bounds__(256, 4) void gemm_prep(
    const float* __restrict__ x, const float* __restrict__ W,
    const float* __restrict__ bias,
    const int* __restrict__ edge_dst, int* __restrict__ row_ptr,
    ushort* __restrict__ support) {
  const int tid  = threadIdx.x;
  const int bid  = blockIdx.x;

  if (bid >= GEMM_BLOCKS) {
    // ---- prep: CSR row_ptr from sorted edge_dst ----
    for (int e = (bid - GEMM_BLOCKS) * 256 + tid; e < N_EDGES;
         e += PREP_BLOCKS * 256) {
      const int d = edge_dst[e];
      if (e == 0) {
        for (int n = 0; n <= d; ++n) row_ptr[n] = 0;
      } else {
        const int dp = edge_dst[e - 1];
        if (d != dp)
          for (int n = dp + 1; n <= d; ++n) row_ptr[n] = e;
      }
      if (e == N_EDGES - 1)
        for (int n = d + 1; n <= N_NODES; ++n) row_ptr[n] = N_EDGES;
    }
    return;
  }

  // ---- gemm ----
  __shared__ ushort Wl[D_OUT * D_IN];  // 32 KB, XOR-swizzled
  const int wave = tid >> 6;
  const int lane = tid & 63;
  const int m0  = bid * 64 + wave * 16;
  const int r16 = lane & 15;
  const int kg  = lane >> 4;
  int arow = m0 + r16;
  if (arow >= N_NODES) arow = N_NODES - 1;   // clamp; stores guarded
  const float* xp = x + (size_t)arow * D_IN + kg * 8;

  // (1) issue the wave's entire A-slice: 16 independent 16B loads.
  f32x4 xd[16];
#pragma unroll
  for (int ks = 0; ks < 8; ++ks) {
    xd[2 * ks]     = *reinterpret_cast<const f32x4*>(xp + ks * 32);
    xd[2 * ks + 1] = *reinterpret_cast<const f32x4*>(xp + ks * 32 + 4);
  }
  // (2) scheduling fence: nothing crosses; the 16 loads stay issued & live.
  __builtin_amdgcn_sched_barrier(0);

  // (3) W -> LDS under the x-miss latency.
  for (int c = tid; c < (D_OUT * D_IN) / 8; c += 256) {
    const int row = c >> 5;
    const int cc  = c & 31;
    const f32x4 w0 = *reinterpret_cast<const f32x4*>(W + c * 8);
    const f32x4 w1 = *reinterpret_cast<const f32x4*>(W + c * 8 + 4);
    bf16x8 v;
    v[0] = (short)f2bf(w0[0]); v[1] = (short)f2bf(w0[1]);
    v[2] = (short)f2bf(w0[2]); v[3] = (short)f2bf(w0[3]);
    v[4] = (short)f2bf(w1[0]); v[5] = (short)f2bf(w1[1]);
    v[6] = (short)f2bf(w1[2]); v[7] = (short)f2bf(w1[3]);
    unsigned byte = row * 512 + cc * 16;
    byte ^= (row & 7) << 4;                 // st-swizzle (conflict-free b128)
    *reinterpret_cast<bf16x8*>(reinterpret_cast<char*>(Wl) + byte) = v;
  }
  __syncthreads();

  // (4) consume: convert + MFMA.
  f32x4 acc[4] = {f32x4{0.f,0.f,0.f,0.f}, f32x4{0.f,0.f,0.f,0.f},
                  f32x4{0.f,0.f,0.f,0.f}, f32x4{0.f,0.f,0.f,0.f}};
#pragma unroll
  for (int ks = 0; ks < 8; ++ks) {
    const f32x4 xa = xd[2 * ks];
    const f32x4 xb = xd[2 * ks + 1];
    bf16x8 a;
    a[0] = (short)f2bf(xa[0]); a[1] = (short)f2bf(xa[1]);
    a[2] = (short)f2bf(xa[2]); a[3] = (short)f2bf(xa[3]);
    a[4] = (short)f2bf(xb[0]); a[5] = (short)f2bf(xb[1]);
    a[6] = (short)f2bf(xb[2]); a[7] = (short)f2bf(xb[3]);
#pragma unroll
    for (int nb = 0; nb < 4; ++nb) {
      const int row = nb * 16 + r16;
      unsigned byte = row * 512 + kg * 16 + ks * 64;   // same lane->k map as A
      byte ^= (row & 7) << 4;                          // ld-swizzle
      const bf16x8 bfrag = *reinterpret_cast<const bf16x8*>(
          reinterpret_cast<const char*>(Wl) + byte);
      acc[nb] =
          __builtin_amdgcn_mfma_f32_16x16x32_bf16(a, bfrag, acc[nb], 0, 0, 0);
    }
  }
#pragma unroll
  for (int nb = 0; nb < 4; ++nb) {
    const int col = nb * 16 + r16;
    const float bv = bias[col];
#pragma unroll
    for (int i = 0; i < 4; ++i) {
      const int row = m0 + kg * 4 + i;  // C/D: col=lane&15, row=(lane>>4)*4+reg
      if (row < N_NODES)
        support[(size_t)row * D_OUT + col] = f2bf(acc[nb][i] + bv);
    }
  }
}

// ---------------------------------------------------------------------------
// Aggregation + LeakyReLU — R4 structure (measured ~14-18 µs by subtraction).
// One wave per node, lane = column. 8 independent accumulators -> 8 gathers
// (one 128B row each) in flight. f32 accumulate, fused LeakyReLU.
// ---------------------------------------------------------------------------
__global__ __launch_bounds__(256, 8) void agg_kernel(
    const ushort* __restrict__ support, const int* __restrict__ edge_src,
    const float* __restrict__ edge_val, const int* __restrict__ row_ptr,
    float* __restrict__ out) {
  const int wid = (blockIdx.x * 256 + threadIdx.x) >> 6;
  const int lane = threadIdx.x & 63;
  if (wid >= N_NODES) return;
  const int lo = row_ptr[wid];
  const int hi = row_ptr[wid + 1];

  float a[8];
#pragma unroll
  for (int q = 0; q < 8; ++q) a[q] = 0.f;

  int e = lo;
  for (; e + 7 < hi; e += 8) {
    int   s[8];
    float v[8];
#pragma unroll
    for (int q = 0; q < 8; ++q) { s[q] = edge_src[e + q]; v[q] = edge_val[e + q]; }
#pragma unroll
    for (int q = 0; q < 8; ++q)
      a[q] = fmaf(v[q], bf2f(support[(size_t)s[q] * D_OUT + lane]), a[q]);
  }
  if (e + 3 < hi) {
    int   s[4];
    float v[4];
#pragma unroll
    for (int q = 0; q < 4; ++q) { s[q] = edge_src[e + q]; v[q] = edge_val[e + q]; }
#pragma unroll
    for (int q = 0; q < 4; ++q)
      a[q] = fmaf(v[q], bf2f(support[(size_t)s[q] * D_OUT + lane]), a[q]);
    e += 4;
  }
  for (; e < hi; ++e)
    a[0] = fmaf(edge_val[e], bf2f(support[(size_t)edge_src[e] * D_OUT + lane]), a[0]);

  const float acc = ((a[0] + a[1]) + (a[2] + a[3])) + ((a[4] + a[5]) + (a[6] + a[7]));
  out[(size_t)wid * D_OUT + lane] = acc >= 0.f ? acc : NEG_SLOPE * acc;
}

// ---------------------------------------------------------------------------
extern "C" void kernel_launch(void* const* d_in, const int* in_sizes, int n_in,
                              void* d_out, int out_size, void* d_ws, size_t ws_size,
                              hipStream_t stream) {
  const float* x        = (const float*)d_in[0];
  const float* W        = (const float*)d_in[1];
  const float* b        = (const float*)d_in[2];
  const int*   edge_src = (const int*)d_in[3];
  const int*   edge_dst = (const int*)d_in[4];
  const float* edge_val = (const float*)d_in[5];
  float* out = (float*)d_out;

  // workspace layout
  ushort* support = (ushort*)d_ws;                                  // 6.4 MB
  char* p = (char*)d_ws + (size_t)N_NODES * D_OUT * sizeof(ushort);
  int* row_ptr = (int*)p;                                           // 200 KB

  hipLaunchKernelGGL(gemm_prep, dim3(GRID1), dim3(256), 0, stream,
                     x, W, b, edge_dst, row_ptr, support);
  hipLaunchKernelGGL(agg_kernel, dim3((N_NODES * 64 + 255) / 256), dim3(256), 0,
                     stream, support, edge_src, edge_val, row_ptr, out);
}

// Round 12
// 55.729 us; speedup vs baseline: 9.0540x; 1.0404x over previous
//
#include <hip/hip_runtime.h>

#define N_NODES 50000
#define N_EDGES 800000
#define D_IN 256
#define D_OUT 64
#define NEG_SLOPE 0.2f

#define PREP_BLOCKS 114   // row_ptr builder blocks FIRST (overlap with gemm)
#define GEMM_BLOCKS 782   // ceil(50000/64), one 64-row tile per block
#define GRID1 (PREP_BLOCKS + GEMM_BLOCKS)

typedef __attribute__((ext_vector_type(8))) short bf16x8;   // 8 bf16 = 4 VGPR
typedef __attribute__((ext_vector_type(4))) float f32x4;    // MFMA C/D

__device__ inline ushort f2bf(float f) {  // f32 -> bf16, round-nearest-even
  union { float f; unsigned u; } v; v.f = f;
  unsigned r = v.u + 0x7FFFu + ((v.u >> 16) & 1u);
  return (ushort)(r >> 16);
}
__device__ inline float bf2f(ushort h) {
  union { unsigned u; float f; } v; v.u = ((unsigned)h) << 16;
  return v.f;
}

// Issue one 16B global load via asm volatile: cannot be sunk, deleted, or
// reordered past other memory ops ("memory" clobber). Literal offset.
#define XLOAD(dst, off)                                                  \
  asm volatile("global_load_dwordx4 %0, %1, off offset:" #off            \
               : "=v"(dst) : "v"(xp) : "memory")

// ---------------------------------------------------------------------------
// Kernel 1: blocks <114 build CSR row_ptr (consumed only by the NEXT
// dispatch); blocks >=114 run one 16x64 MFMA tile per wave.
// gemm schedule (the optimization IS the order):
//   1) 16 asm-volatile x-loads back-to-back  -> 16 outstanding HBM loads/wave
//      (R8/R11 showed the compiler otherwise sinks to a 2-deep pipeline:
//       VGPR_Count stayed 48; asm forces ~64 data VGPRs live)
//   2) W f32->bf16 into XOR-swizzled LDS under the x-miss latency
//   3) syncthreads; s_waitcnt vmcnt(0); sched_barrier(0)   [rule #18 fence]
//   4) pure register+LDS compute: convert + 32 MFMA, epilogue.
// ---------------------------------------------------------------------------
__global__ __launch_bounds__(256, 4) void gemm_prep(
    const float* __restrict__ x, const float* __restrict__ W,
    const float* __restrict__ bias,
    const int* __restrict__ edge_dst, int* __restrict__ row_ptr,
    ushort* __restrict__ support) {
  const int tid  = threadIdx.x;
  const int bid  = blockIdx.x;

  if (bid < PREP_BLOCKS) {
    // ---- prep: CSR row_ptr from sorted edge_dst ----
    for (int e = bid * 256 + tid; e < N_EDGES; e += PREP_BLOCKS * 256) {
      const int d = edge_dst[e];
      if (e == 0) {
        for (int n = 0; n <= d; ++n) row_ptr[n] = 0;
      } else {
        const int dp = edge_dst[e - 1];
        if (d != dp)
          for (int n = dp + 1; n <= d; ++n) row_ptr[n] = e;
      }
      if (e == N_EDGES - 1)
        for (int n = d + 1; n <= N_NODES; ++n) row_ptr[n] = N_EDGES;
    }
    return;
  }

  // ---- gemm ----
  __shared__ ushort Wl[D_OUT * D_IN];  // 32 KB, XOR-swizzled
  const int wave = tid >> 6;
  const int lane = tid & 63;
  const int m0  = (bid - PREP_BLOCKS) * 64 + wave * 16;
  const int r16 = lane & 15;
  const int kg  = lane >> 4;
  int arow = m0 + r16;
  if (arow >= N_NODES) arow = N_NODES - 1;   // clamp; stores guarded
  const float* xp = x + (size_t)arow * D_IN + kg * 8;

  // (1) the wave's entire A-slice: 16 independent 16B loads, forced in flight.
  f32x4 xd[16];
  XLOAD(xd[0], 0);    XLOAD(xd[1], 16);
  XLOAD(xd[2], 128);  XLOAD(xd[3], 144);
  XLOAD(xd[4], 256);  XLOAD(xd[5], 272);
  XLOAD(xd[6], 384);  XLOAD(xd[7], 400);
  XLOAD(xd[8], 512);  XLOAD(xd[9], 528);
  XLOAD(xd[10], 640); XLOAD(xd[11], 656);
  XLOAD(xd[12], 768); XLOAD(xd[13], 784);
  XLOAD(xd[14], 896); XLOAD(xd[15], 912);

  // (2) W -> LDS under the x-miss latency (W is L2/L3-hot after first blocks).
  for (int c = tid; c < (D_OUT * D_IN) / 8; c += 256) {
    const int row = c >> 5;
    const int cc  = c & 31;
    const f32x4 w0 = *reinterpret_cast<const f32x4*>(W + c * 8);
    const f32x4 w1 = *reinterpret_cast<const f32x4*>(W + c * 8 + 4);
    bf16x8 v;
    v[0] = (short)f2bf(w0[0]); v[1] = (short)f2bf(w0[1]);
    v[2] = (short)f2bf(w0[2]); v[3] = (short)f2bf(w0[3]);
    v[4] = (short)f2bf(w1[0]); v[5] = (short)f2bf(w1[1]);
    v[6] = (short)f2bf(w1[2]); v[7] = (short)f2bf(w1[3]);
    unsigned byte = row * 512 + cc * 16;
    byte ^= (row & 7) << 4;                 // st-swizzle (conflict-free b128)
    *reinterpret_cast<bf16x8*>(reinterpret_cast<char*>(Wl) + byte) = v;
  }
  __syncthreads();

  // (3) drain my asm loads; fence so no consumer is hoisted above (rule #18).
  asm volatile("s_waitcnt vmcnt(0)" ::: "memory");
  __builtin_amdgcn_sched_barrier(0);

  // (4) consume: convert + MFMA, all register/LDS traffic.
  f32x4 acc[4] = {f32x4{0.f,0.f,0.f,0.f}, f32x4{0.f,0.f,0.f,0.f},
                  f32x4{0.f,0.f,0.f,0.f}, f32x4{0.f,0.f,0.f,0.f}};
#pragma unroll
  for (int ks = 0; ks < 8; ++ks) {
    const f32x4 xa = xd[2 * ks];
    const f32x4 xb = xd[2 * ks + 1];
    bf16x8 a;
    a[0] = (short)f2bf(xa[0]); a[1] = (short)f2bf(xa[1]);
    a[2] = (short)f2bf(xa[2]); a[3] = (short)f2bf(xa[3]);
    a[4] = (short)f2bf(xb[0]); a[5] = (short)f2bf(xb[1]);
    a[6] = (short)f2bf(xb[2]); a[7] = (short)f2bf(xb[3]);
#pragma unroll
    for (int nb = 0; nb < 4; ++nb) {
      const int row = nb * 16 + r16;
      unsigned byte = row * 512 + kg * 16 + ks * 64;   // same lane->k map as A
      byte ^= (row & 7) << 4;                          // ld-swizzle
      const bf16x8 bfrag = *reinterpret_cast<const bf16x8*>(
          reinterpret_cast<const char*>(Wl) + byte);
      acc[nb] =
          __builtin_amdgcn_mfma_f32_16x16x32_bf16(a, bfrag, acc[nb], 0, 0, 0);
    }
  }
#pragma unroll
  for (int nb = 0; nb < 4; ++nb) {
    const int col = nb * 16 + r16;
    const float bv = bias[col];
#pragma unroll
    for (int i = 0; i < 4; ++i) {
      const int row = m0 + kg * 4 + i;  // C/D: col=lane&15, row=(lane>>4)*4+reg
      if (row < N_NODES)
        support[(size_t)row * D_OUT + col] = f2bf(acc[nb][i] + bv);
    }
  }
}

// ---------------------------------------------------------------------------
// Aggregation + LeakyReLU — R4 structure (~15 µs by subtraction).
// One wave per node, lane = column. 8 independent accumulators -> 8 gathers
// (one 128B row each) in flight. f32 accumulate, fused LeakyReLU.
// ---------------------------------------------------------------------------
__global__ __launch_bounds__(256, 8) void agg_kernel(
    const ushort* __restrict__ support, const int* __restrict__ edge_src,
    const float* __restrict__ edge_val, const int* __restrict__ row_ptr,
    float* __restrict__ out) {
  const int wid = (blockIdx.x * 256 + threadIdx.x) >> 6;
  const int lane = threadIdx.x & 63;
  if (wid >= N_NODES) return;
  const int lo = row_ptr[wid];
  const int hi = row_ptr[wid + 1];

  float a[8];
#pragma unroll
  for (int q = 0; q < 8; ++q) a[q] = 0.f;

  int e = lo;
  for (; e + 7 < hi; e += 8) {
    int   s[8];
    float v[8];
#pragma unroll
    for (int q = 0; q < 8; ++q) { s[q] = edge_src[e + q]; v[q] = edge_val[e + q]; }
#pragma unroll
    for (int q = 0; q < 8; ++q)
      a[q] = fmaf(v[q], bf2f(support[(size_t)s[q] * D_OUT + lane]), a[q]);
  }
  if (e + 3 < hi) {
    int   s[4];
    float v[4];
#pragma unroll
    for (int q = 0; q < 4; ++q) { s[q] = edge_src[e + q]; v[q] = edge_val[e + q]; }
#pragma unroll
    for (int q = 0; q < 4; ++q)
      a[q] = fmaf(v[q], bf2f(support[(size_t)s[q] * D_OUT + lane]), a[q]);
    e += 4;
  }
  for (; e < hi; ++e)
    a[0] = fmaf(edge_val[e], bf2f(support[(size_t)edge_src[e] * D_OUT + lane]), a[0]);

  const float acc = ((a[0] + a[1]) + (a[2] + a[3])) + ((a[4] + a[5]) + (a[6] + a[7]));
  out[(size_t)wid * D_OUT + lane] = acc >= 0.f ? acc : NEG_SLOPE * acc;
}

// ---------------------------------------------------------------------------
extern "C" void kernel_launch(void* const* d_in, const int* in_sizes, int n_in,
                              void* d_out, int out_size, void* d_ws, size_t ws_size,
                              hipStream_t stream) {
  const float* x        = (const float*)d_in[0];
  const float* W        = (const float*)d_in[1];
  const float* b        = (const float*)d_in[2];
  const int*   edge_src = (const int*)d_in[3];
  const int*   edge_dst = (const int*)d_in[4];
  const float* edge_val = (const float*)d_in[5];
  float* out = (float*)d_out;

  // workspace layout
  ushort* support = (ushort*)d_ws;                                  // 6.4 MB
  char* p = (char*)d_ws + (size_t)N_NODES * D_OUT * sizeof(ushort);
  int* row_ptr = (int*)p;                                           // 200 KB

  hipLaunchKernelGGL(gemm_prep, dim3(GRID1), dim3(256), 0, stream,
                     x, W, b, edge_dst, row_ptr, support);
  hipLaunchKernelGGL(agg_kernel, dim3((N_NODES * 64 + 255) / 256), dim3(256), 0,
                     stream, support, edge_src, edge_val, row_ptr, out);
}